// Round 1
// baseline (53.995 us; speedup 1.0000x reference)
//
#include <hip/hip_runtime.h>

#define BTOT 4096
#define G 8            // batch items per block
#define NC 16
#define WIN 247
#define KPAD 250
#define WST 251        // LDS stride for W rows (odd -> conflict-free)
#define NW 10
#define NBLK (BTOT / G)   // 512

// ---------------- Kernel 1: conv + nonlinearity + projections + partials ----------------
__global__ __launch_bounds__(256) void k_main(
    const float* __restrict__ x,
    const float* __restrict__ Wr, const float* __restrict__ Wi,
    const float* __restrict__ Wnl, const float* __restrict__ Wc,
    const float* __restrict__ Wor, const float* __restrict__ Woi,
    float* __restrict__ out, float* __restrict__ ws)
{
    __shared__ float Wlds[2 * NC * WST];   // [ri][c][k], 8032 words
    __shared__ float fbuf[G * 32 * NW];    // [b][cri][w], 2560 words
    __shared__ float WnlS[NC * 2 * 30];    // 960
    __shared__ float WoS[2 * 160];         // real then imag
    __shared__ float WcS[4];
    __shared__ float red[256];
    __shared__ float redq[128];

    float* crS = Wlds;          // alias: G*160 = 1280 (safe after phase-1 barrier)
    float* ciS = Wlds + 1280;   // 1280

    const int tid = threadIdx.x;
    const int b0 = blockIdx.x * G;

    // ---- stage weights ----
    for (int idx = tid; idx < 2 * NC * KPAD; idx += 256) {
        int ri  = idx / (NC * KPAD);
        int rem = idx - ri * (NC * KPAD);
        int c   = rem / KPAD;
        int k   = rem - c * KPAD;
        float v = 0.f;
        if (k < WIN) v = ri ? Wi[c * WIN + k] : Wr[c * WIN + k];
        Wlds[ri * (NC * WST) + c * WST + k] = v;
    }
    for (int idx = tid; idx < NC * 60; idx += 256) WnlS[idx] = Wnl[idx];
    if (tid < 160) { WoS[tid] = Wor[tid]; WoS[160 + tid] = Woi[tid]; }
    if (tid < 4) WcS[tid] = Wc[tid];
    __syncthreads();

    // ---- phase 1: depthwise sliding dot products ----
    {
        const int b_loc = tid >> 5;       // 0..7
        const int cri   = tid & 31;       // c*2+ri
        const int ri    = cri & 1;
        const int c     = cri >> 1;
        const float* xb = x + (size_t)(b0 + b_loc) * 8192 + cri;  // x[b,n,c,ri] = base + n*32
        const float* Wrow = Wlds + ri * (NC * WST) + c * WST;

        float acc[NW];
        float xb10[NW];
        #pragma unroll
        for (int w = 0; w < NW; ++w) { acc[w] = 0.f; xb10[w] = xb[w * 32]; }

        // main: i = 0..239 (all steps load x[i+10])
        for (int i0 = 0; i0 < 240; i0 += NW) {
            #pragma unroll
            for (int j = 0; j < NW; ++j) {
                float wv = Wrow[i0 + j];
                #pragma unroll
                for (int w = 0; w < NW; ++w)
                    acc[w] = fmaf(xb10[(j + w) % NW], wv, acc[w]);
                xb10[j] = xb[(i0 + j + NW) * 32];
            }
        }
        // tail: i = 240..249 ; W[247..249]=0 ; load x[250..255] for j<6
        #pragma unroll
        for (int j = 0; j < NW; ++j) {
            float wv = Wrow[240 + j];
            #pragma unroll
            for (int w = 0; w < NW; ++w)
                acc[w] = fmaf(xb10[(j + w) % NW], wv, acc[w]);
            if (j < 6) xb10[j] = xb[(240 + j + NW) * 32];
        }

        #pragma unroll
        for (int w = 0; w < NW; ++w)
            fbuf[tid * NW + w] = acc[w];
    }
    __syncthreads();

    // ---- phase 2: amp nonlinearity, in place ----
    for (int idx = tid; idx < G * 160; idx += 256) {
        int b = idx / 160; int r = idx - b * 160;
        int c = r / NW;    int w = r - c * NW;
        int base = b * 320 + c * 20 + w;
        float fr = fbuf[base];
        float fi = fbuf[base + NW];
        float amp = fr * fr + fi * fi;
        fbuf[base]      = amp * fr;
        fbuf[base + NW] = amp * fi;
    }
    __syncthreads();

    // ---- phase 3: neighbor einsum + coeff + output window weights ----
    for (int idx = tid; idx < G * 160; idx += 256) {
        int b = idx / 160; int r = idx - b * 160;
        int c = r / NW;    int w = r - c * NW;
        const float* f3b = fbuf + b * 320;
        const float* wn  = WnlS + c * 60;
        float s0 = 0.f, s1 = 0.f;
        #pragma unroll
        for (int j = 0; j < NC; ++j) {
            if (j != c) {
                int jj = (j > c) ? (j - 1) : j;
                float f3r = f3b[j * 20 + w];
                float f3i = f3b[j * 20 + NW + w];
                s0 += f3r * wn[jj]      + f3i * wn[15 + jj];
                s1 += f3r * wn[30 + jj] + f3i * wn[45 + jj];
            }
        }
        float p0 = s0 * WcS[0] + s1 * WcS[1];   // p=0
        float p1 = s0 * WcS[2] + s1 * WcS[3];   // p=1
        crS[idx] = p0 * WoS[c * NW + w];
        ciS[idx] = p1 * WoS[160 + c * NW + w];
    }
    __syncthreads();

    // ---- phase 4: sum over w, write out, block partials ----
    if (tid < G * NC) {
        int b = tid >> 4; int c = tid & 15;
        float orr = 0.f, oii = 0.f;
        #pragma unroll
        for (int w = 0; w < NW; ++w) {
            orr += crS[b * 160 + c * NW + w];
            oii += ciS[b * 160 + c * NW + w];
        }
        size_t o = ((size_t)(b0 + b) * NC + c) * 2;
        out[o]     = orr;
        out[o + 1] = oii;
        red[tid]       = orr + oii;
        redq[tid]      = orr * orr + oii * oii;
    }
    __syncthreads();
    if (tid < NC) {
        float s = 0.f, q = 0.f;
        #pragma unroll
        for (int b = 0; b < G; ++b) { s += red[b * 16 + tid]; q += redq[b * 16 + tid]; }
        ws[(tid * NBLK + blockIdx.x) * 2]     = s;
        ws[(tid * NBLK + blockIdx.x) * 2 + 1] = q;
    }
}

// ---------------- Kernel 2: reduce partials -> per-channel scale/shift ----------------
__global__ __launch_bounds__(256) void k_bnstat(
    const float* __restrict__ ws_in, float* __restrict__ ws_ab,
    const float* __restrict__ gamma, const float* __restrict__ beta)
{
    const int c = blockIdx.x;
    const int tid = threadIdx.x;
    float s = 0.f, q = 0.f;
    for (int i = tid; i < NBLK; i += 256) {
        s += ws_in[(c * NBLK + i) * 2];
        q += ws_in[(c * NBLK + i) * 2 + 1];
    }
    #pragma unroll
    for (int off = 32; off; off >>= 1) {
        s += __shfl_down(s, off, 64);
        q += __shfl_down(q, off, 64);
    }
    __shared__ float rs[4], rq[4];
    const int wv = tid >> 6;
    if ((tid & 63) == 0) { rs[wv] = s; rq[wv] = q; }
    __syncthreads();
    if (tid == 0) {
        s = rs[0] + rs[1] + rs[2] + rs[3];
        q = rq[0] + rq[1] + rq[2] + rq[3];
        const float inv_n = 1.f / (BTOT * 2.f);
        float mu  = s * inv_n;
        float var = q * inv_n - mu * mu;
        float sc  = gamma[c] * rsqrtf(var + 1e-5f);
        ws_ab[c]      = sc;
        ws_ab[16 + c] = beta[c] - mu * sc;
    }
}

// ---------------- Kernel 3: apply BN affine in place ----------------
__global__ __launch_bounds__(256) void k_bnapply(
    float* __restrict__ out, const float* __restrict__ ws_ab)
{
    __shared__ float A[16], Bb[16];
    const int tid = threadIdx.x;
    if (tid < 16) { A[tid] = ws_ab[tid]; Bb[tid] = ws_ab[16 + tid]; }
    __syncthreads();
    int idx = blockIdx.x * 256 + tid;
    if (idx < BTOT * NC * 2) {
        int c = (idx >> 1) & 15;
        out[idx] = out[idx] * A[c] + Bb[c];
    }
}

extern "C" void kernel_launch(void* const* d_in, const int* in_sizes, int n_in,
                              void* d_out, int out_size, void* d_ws, size_t ws_size,
                              hipStream_t stream)
{
    const float* x    = (const float*)d_in[0];
    const float* Wr   = (const float*)d_in[1];
    const float* Wi   = (const float*)d_in[2];
    const float* Wnl  = (const float*)d_in[3];
    const float* Wc   = (const float*)d_in[4];
    const float* Wor  = (const float*)d_in[5];
    const float* Woi  = (const float*)d_in[6];
    const float* gam  = (const float*)d_in[7];
    const float* bet  = (const float*)d_in[8];
    float* out = (float*)d_out;
    float* ws  = (float*)d_ws;
    float* ws_ab = ws + NC * NBLK * 2;   // 16384 floats of partials, then 32 floats scale/shift

    k_main<<<NBLK, 256, 0, stream>>>(x, Wr, Wi, Wnl, Wc, Wor, Woi, out, ws);
    k_bnstat<<<NC, 256, 0, stream>>>(ws, ws_ab, gam, bet);
    k_bnapply<<<(BTOT * NC * 2 + 255) / 256, 256, 0, stream>>>(out, ws_ab);
}